// Round 3
// baseline (596.166 us; speedup 1.0000x reference)
//
#include <hip/hip_runtime.h>
#include <math.h>

// Shapes: B=32, S=512, I=64, H=512, E=8, P=96, O=64, EM=512; D = S*I = 32768.
#define DIMK 32768

__device__ __forceinline__ void fma4(float4& a, float s, const float4 w) {
  a.x += s * w.x; a.y += s * w.y; a.z += s * w.z; a.w += s * w.w;
}

__device__ __forceinline__ float block_sum(float v, float* red, int n) {
  int t = threadIdx.x;
  red[t] = v;
  __syncthreads();
  for (int s = n >> 1; s > 0; s >>= 1) {
    if (t < s) red[t] += red[t + s];
    __syncthreads();
  }
  float r = red[0];
  __syncthreads();
  return r;
}

// ---------------------------------------------------------------------------
// Kernel 1: y1_partial = x_flat(32,32768) @ gW1(32768,512), k-split.
// grid (4 m-tiles of 128 cols, 128 k-chunks of 256), block 512 (8 waves).
__global__ __launch_bounds__(512, 4) void gemm1_part(const float* __restrict__ x,
                                                     const float* __restrict__ gW1,
                                                     float* __restrict__ part) {
  const int mt = blockIdx.x;      // 0..3
  const int ks = blockIdx.y;      // 0..127
  const int m0 = mt * 128;
  const int k0 = ks * 256;
  const int t = threadIdx.x;
  const int cg = t & 31;          // 32 col-groups * 4 cols = 128 cols
  const int rh = t >> 5;          // 0..15
  const int rbase = (rh & 1) * 4; // float4-group base: rows 0-15 or 16-31
  const int par = rh >> 1;        // k parity 0..7
  __shared__ float4 xs4[256][9];  // [kk][b/4], row stride 36 floats
  __shared__ float4 red4[512];

  float4 acc[16];
#pragma unroll
  for (int r = 0; r < 16; ++r) acc[r] = make_float4(0.f, 0.f, 0.f, 0.f);

  float* xsf = (float*)xs4;
  for (int i = t; i < 32 * 256; i += 512) {
    int bb = i >> 8, kk = i & 255;
    xsf[kk * 36 + bb] = x[(size_t)bb * DIMK + k0 + kk];
  }
  __syncthreads();

  const float* gp = gW1 + (size_t)k0 * 512 + m0 + cg * 4;
#pragma unroll 2
  for (int kk = par; kk < 256; kk += 8) {
    float4 wv = *(const float4*)(gp + (size_t)kk * 512);
    const float4* xr = &xs4[kk][rbase];
#pragma unroll
    for (int j = 0; j < 4; ++j) {
      float4 xv = xr[j];
      fma4(acc[j * 4 + 0], xv.x, wv);
      fma4(acc[j * 4 + 1], xv.y, wv);
      fma4(acc[j * 4 + 2], xv.z, wv);
      fma4(acc[j * 4 + 3], xv.w, wv);
    }
  }

  for (int r = 0; r < 16; ++r) {
    __syncthreads();
    red4[t] = acc[r];
    __syncthreads();
    if (t < 64) {
      float4 s = red4[t];
#pragma unroll
      for (int p = 1; p < 8; ++p) {
        float4 q = red4[t + 64 * p];
        s.x += q.x; s.y += q.y; s.z += q.z; s.w += q.w;
      }
      int row = (t >> 5) * 16 + r;
      *(float4*)(part + ((size_t)ks * 32 + row) * 512 + m0 + (t & 31) * 4) = s;
    }
  }
}

// ---------------------------------------------------------------------------
// gred_ln: h1 = relu(LN(sum_ks part + gb1)). grid 32, block 512.
__global__ __launch_bounds__(512) void gred_ln(const float* __restrict__ part,
                                               const float* __restrict__ gb1,
                                               const float* __restrict__ g, const float* __restrict__ bt,
                                               float* __restrict__ h1) {
  const int b = blockIdx.x, t = threadIdx.x;
  __shared__ float red[512];
  float a = gb1[t];
  const float* pp0 = part + (size_t)b * 512 + t;
#pragma unroll 16
  for (int ks = 0; ks < 128; ++ks) a += pp0[(size_t)ks * 16384];
  float mean = block_sum(a, red, 512) * (1.f / 512.f);
  float d = a - mean;
  float var = block_sum(d * d, red, 512) * (1.f / 512.f);
  h1[b * 512 + t] = fmaxf(d * rsqrtf(var + 1e-5f) * g[t] + bt[t], 0.f);
}

// ---------------------------------------------------------------------------
// gemm_bat: batched-over-b small GEMM, k-split. C_part = A(32x512) @ W(512xM).
// grid (MT = M/128, KQ = 4, E), block 256. Thread: 4 b x 4 cols (float4).
// Weights are read exactly once across the whole grid (b-batched in-block).
__global__ __launch_bounds__(256) void gemm_bat(const float* __restrict__ A,
                                                const float* __restrict__ W,
                                                float* __restrict__ outp,
                                                int M, size_t aStrideE, size_t wStrideE) {
  const int mt = blockIdx.x, kq = blockIdx.y, ez = blockIdx.z, EB = gridDim.z;
  const int k0 = kq * 128, m0 = mt * 128;
  const int t = threadIdx.x;
  const int mf = t & 31, bg = t >> 5;
  __shared__ float As[32 * 132];  // pad 132 -> bank (4b+kk)%32, conflict-free
  const float* Ae = A + (size_t)ez * aStrideE;
  for (int i = t; i < 4096; i += 256) {
    int b = i >> 7, kk = i & 127;
    As[b * 132 + kk] = Ae[(size_t)b * 512 + k0 + kk];
  }
  __syncthreads();
  float4 acc[4];
#pragma unroll
  for (int j = 0; j < 4; ++j) acc[j] = make_float4(0.f, 0.f, 0.f, 0.f);
  const float* Wp = W + (size_t)ez * wStrideE + (size_t)k0 * M + m0 + mf * 4;
  const float* a0 = As + (bg * 4) * 132;
#pragma unroll 8
  for (int kk = 0; kk < 128; ++kk) {
    float4 wv = *(const float4*)(Wp + (size_t)kk * M);
    fma4(acc[0], a0[kk], wv);
    fma4(acc[1], a0[132 + kk], wv);
    fma4(acc[2], a0[264 + kk], wv);
    fma4(acc[3], a0[396 + kk], wv);
  }
  float* op = outp + ((size_t)(kq * EB + ez) * 32 + bg * 4) * M + m0 + mf * 4;
#pragma unroll
  for (int j = 0; j < 4; ++j) *(float4*)(op + (size_t)j * M) = acc[j];
}

// ---------------------------------------------------------------------------
// red_ln: out = [relu](LN(sum_kq zp + bias)). grid 32, block M (512 or 256).
__global__ void red_ln(const float* __restrict__ zp, const float* __restrict__ bias,
                       const float* __restrict__ g, const float* __restrict__ bt,
                       float* __restrict__ outp, int M, int relu) {
  const int b = blockIdx.x, t = threadIdx.x;
  __shared__ float red[512];
  float a = bias[t];
#pragma unroll
  for (int kq = 0; kq < 4; ++kq) a += zp[((size_t)kq * 32 + b) * M + t];
  float fM = 1.f / (float)M;
  float mean = block_sum(a, red, M) * fM;
  float d = a - mean;
  float var = block_sum(d * d, red, M) * fM;
  float v = d * rsqrtf(var + 1e-5f) * g[t] + bt[t];
  outp[b * M + t] = relu ? fmaxf(v, 0.f) : v;
}

// ---------------------------------------------------------------------------
// gate_k: emb = sum_kq zp2 + gb3; d2 to protos; softmax -> wgt. grid 32, block 128.
__global__ __launch_bounds__(128) void gate_k(const float* __restrict__ zp2,
                                              const float* __restrict__ gb3,
                                              const float* __restrict__ protos,
                                              const float* __restrict__ temp,
                                              float* __restrict__ wgt) {
  __shared__ float red[128];
  __shared__ float d2s[8];
  const int b = blockIdx.x, t = threadIdx.x;
  float a = gb3[t];
#pragma unroll
  for (int kq = 0; kq < 4; ++kq) a += zp2[((size_t)kq * 32 + b) * 128 + t];
  for (int e = 0; e < 8; ++e) {
    float dd = a - protos[e * 128 + t];
    float s = block_sum(dd * dd, red, 128);
    if (t == 0) d2s[e] = s;
  }
  __syncthreads();
  if (t == 0) {
    float tt = fminf(fmaxf(temp[0], 0.1f), 5.0f);
    float lg[8], mx = -1e30f;
#pragma unroll
    for (int e = 0; e < 8; ++e) {
      float dist = sqrtf(fmaxf(d2s[e], 1e-12f));
      lg[e] = -dist / tt;
      mx = fmaxf(mx, lg[e]);
    }
    float se = 0.f;
#pragma unroll
    for (int e = 0; e < 8; ++e) { lg[e] = expf(lg[e] - mx); se += lg[e]; }
#pragma unroll
    for (int e = 0; e < 8; ++e) wgt[b * 8 + e] = lg[e] / se;
  }
}

// ---------------------------------------------------------------------------
// he_k: he_all[e][b][h] = relu(x_last[b] . eW1[e][:,h] + eb1[e][h]).
// grid (8 e, 2 h-halves), block 256. Thread: one h, all 32 b in registers.
__global__ __launch_bounds__(256) void he_k(const float* __restrict__ x,
                                            const float* __restrict__ eW1,
                                            const float* __restrict__ eb1,
                                            float* __restrict__ he_all) {
  const int e = blockIdx.x, hs = blockIdx.y;
  const int t = threadIdx.x;
  const int h = hs * 256 + t;
  __shared__ float xs[32 * 64];
  for (int i = t; i < 2048; i += 256) {
    int b = i >> 6, ii = i & 63;
    xs[i] = x[(size_t)b * DIMK + 32704 + ii];
  }
  __syncthreads();
  float acc[32];
#pragma unroll
  for (int b = 0; b < 32; ++b) acc[b] = 0.f;
  const float* w1 = eW1 + (size_t)e * 64 * 512 + h;
#pragma unroll 4
  for (int k = 0; k < 64; ++k) {
    float wk = w1[(size_t)k * 512];
#pragma unroll
    for (int b = 0; b < 32; ++b) acc[b] += xs[b * 64 + k] * wk;
  }
  float bb = eb1[e * 512 + h];
  for (int b = 0; b < 32; ++b)
    he_all[((size_t)e * 32 + b) * 512 + h] = fmaxf(acc[b] + bb, 0.f);
}

// ---------------------------------------------------------------------------
// ffuse: fused[b] = sum_e w[b,e]*(sum_kq epart[kq][e][b] + eb2[e]). grid 32, block 512.
__global__ __launch_bounds__(512) void ffuse(const float* __restrict__ epart,
                                             const float* __restrict__ eb2,
                                             const float* __restrict__ wgt,
                                             float* __restrict__ fused) {
  const int b = blockIdx.x, t = threadIdx.x;
  __shared__ float wl[8];
  if (t < 8) wl[t] = wgt[b * 8 + t];
  __syncthreads();
  float a = 0.f;
#pragma unroll
  for (int e = 0; e < 8; ++e) {
    float s = eb2[e * 512 + t];
#pragma unroll
    for (int kq = 0; kq < 4; ++kq)
      s += epart[(((size_t)kq * 8 + e) * 32 + b) * 512 + t];
    a += wl[e] * s;
  }
  fused[b * 512 + t] = a;
}

// ---------------------------------------------------------------------------
// final9: p = pp(32x256)@pW2(256x6144)+pb2 -> (32,96,64) -> LN over O=64.
// grid 96 (pi), block 256: wave = b-quad; all 4 quads share one pW2 stream (L1 hits).
__global__ __launch_bounds__(256) void final9(const float* __restrict__ pp,
                                              const float* __restrict__ pW2,
                                              const float* __restrict__ pb2,
                                              const float* __restrict__ ong,
                                              const float* __restrict__ onb,
                                              float* __restrict__ outp) {
  const int pi = blockIdx.x;  // 0..95
  const int t = threadIdx.x;
  const int lane = t & 63, bq = t >> 6;
  const int o4 = lane & 15, bsub = lane >> 4;
  __shared__ float ppl[256 * 33];  // [k][b], pad 33 -> conflict-free
  for (int i = t; i < 8192; i += 256) {
    int bb = i >> 8, k = i & 255;
    ppl[k * 33 + bb] = pp[bb * 256 + k];
  }
  __syncthreads();
  const int b0 = bq * 8 + bsub * 2;
  const int o = pi * 64 + o4 * 4;
  float4 a0 = make_float4(0.f, 0.f, 0.f, 0.f), a1 = a0;
  const float* wp = pW2 + o;
#pragma unroll 8
  for (int k = 0; k < 256; ++k) {
    float4 wv = *(const float4*)(wp + (size_t)k * 6144);
    fma4(a0, ppl[k * 33 + b0], wv);
    fma4(a1, ppl[k * 33 + b0 + 1], wv);
  }
  float4 bias = *(const float4*)(pb2 + o);
  a0.x += bias.x; a0.y += bias.y; a0.z += bias.z; a0.w += bias.w;
  a1.x += bias.x; a1.y += bias.y; a1.z += bias.z; a1.w += bias.w;

  float4 gv = *(const float4*)(ong + o4 * 4);
  float4 bv = *(const float4*)(onb + o4 * 4);
  float4 accs[2] = {a0, a1};
#pragma unroll
  for (int rr = 0; rr < 2; ++rr) {
    float4 a = accs[rr];
    float s = a.x + a.y + a.z + a.w;
    s += __shfl_xor(s, 1); s += __shfl_xor(s, 2);
    s += __shfl_xor(s, 4); s += __shfl_xor(s, 8);
    float mean = s * (1.f / 64.f);
    float d0 = a.x - mean, d1 = a.y - mean, d2 = a.z - mean, d3 = a.w - mean;
    float q = d0 * d0 + d1 * d1 + d2 * d2 + d3 * d3;
    q += __shfl_xor(q, 1); q += __shfl_xor(q, 2);
    q += __shfl_xor(q, 4); q += __shfl_xor(q, 8);
    float r = rsqrtf(q * (1.f / 64.f) + 1e-5f);
    float4 res;
    res.x = d0 * r * gv.x + bv.x;
    res.y = d1 * r * gv.y + bv.y;
    res.z = d2 * r * gv.z + bv.z;
    res.w = d3 * r * gv.w + bv.w;
    int b = b0 + rr;
    *(float4*)(outp + ((size_t)b * 96 + pi) * 64 + o4 * 4) = res;
  }
}

extern "C" void kernel_launch(void* const* d_in, const int* in_sizes, int n_in,
                              void* d_out, int out_size, void* d_ws, size_t ws_size,
                              hipStream_t stream) {
  (void)in_sizes; (void)n_in; (void)out_size; (void)ws_size;
  const float* x      = (const float*)d_in[0];
  const float* gW1    = (const float*)d_in[1];
  const float* gb1    = (const float*)d_in[2];
  const float* gln1_g = (const float*)d_in[3];
  const float* gln1_b = (const float*)d_in[4];
  const float* gW2    = (const float*)d_in[5];
  const float* gb2    = (const float*)d_in[6];
  const float* gln2_g = (const float*)d_in[7];
  const float* gln2_b = (const float*)d_in[8];
  const float* gW3    = (const float*)d_in[9];
  const float* gb3    = (const float*)d_in[10];
  const float* protos = (const float*)d_in[11];
  const float* temp   = (const float*)d_in[12];
  const float* eW1    = (const float*)d_in[13];
  const float* eb1    = (const float*)d_in[14];
  const float* eW2    = (const float*)d_in[15];
  const float* eb2    = (const float*)d_in[16];
  const float* fW1    = (const float*)d_in[17];
  const float* fb1    = (const float*)d_in[18];
  const float* fln_g  = (const float*)d_in[19];
  const float* fln_b  = (const float*)d_in[20];
  const float* fW2    = (const float*)d_in[21];
  const float* fb2    = (const float*)d_in[22];
  const float* ln_g   = (const float*)d_in[23];
  const float* ln_b   = (const float*)d_in[24];
  const float* pW1    = (const float*)d_in[25];
  const float* pb1    = (const float*)d_in[26];
  const float* pln_g  = (const float*)d_in[27];
  const float* pln_b  = (const float*)d_in[28];
  const float* pW2    = (const float*)d_in[29];
  const float* pb2    = (const float*)d_in[30];
  const float* on_g   = (const float*)d_in[31];
  const float* on_b   = (const float*)d_in[32];
  float* out = (float*)d_out;

  float* ws     = (float*)d_ws;
  float* part   = ws;                 // 2,097,152 floats; consumed by gred_ln, then reused:
  float* epart  = part;               //   epart: 4*8*32*512 = 524288 floats
  float* he_all = part + 524288;      //   he_all: 8*32*512 = 131072 floats (disjoint)
  float* h1     = ws + 2097152;       // 16384
  float* h2     = h1 + 16384;         // 16384
  float* zp     = h2 + 16384;         // 65536 (4 kq x 32 x 512)
  float* zp2    = zp + 65536;         // 16384 (4 kq x 32 x 128)
  float* wgt    = zp2 + 16384;        // 256
  float* fused  = wgt + 256;          // 16384
  float* f1     = fused + 16384;      // 16384
  float* lastv  = f1 + 16384;         // 16384
  float* pp     = lastv + 16384;      // 8192   (total ~2.3 M floats = 9.2 MB)

  // g-path (consumes part before the expert path reuses that region)
  gemm1_part<<<dim3(4, 128), 512, 0, stream>>>(x, gW1, part);
  gred_ln<<<32, 512, 0, stream>>>(part, gb1, gln1_g, gln1_b, h1);
  gemm_bat<<<dim3(4, 4, 1), 256, 0, stream>>>(h1, gW2, zp, 512, 0, 0);
  red_ln<<<32, 512, 0, stream>>>(zp, gb2, gln2_g, gln2_b, h2, 512, 1);
  gemm_bat<<<dim3(1, 4, 1), 256, 0, stream>>>(h2, gW3, zp2, 128, 0, 0);
  gate_k<<<32, 128, 0, stream>>>(zp2, gb3, protos, temp, wgt);

  // expert path (reuses the part region)
  he_k<<<dim3(8, 2), 256, 0, stream>>>(x, eW1, eb1, he_all);
  gemm_bat<<<dim3(4, 4, 8), 256, 0, stream>>>(he_all, eW2, epart, 512,
                                              32 * 512, (size_t)512 * 512);
  ffuse<<<32, 512, 0, stream>>>(epart, eb2, wgt, fused);

  // f-path
  gemm_bat<<<dim3(4, 4, 1), 256, 0, stream>>>(fused, fW1, zp, 512, 0, 0);
  red_ln<<<32, 512, 0, stream>>>(zp, fb1, fln_g, fln_b, f1, 512, 1);
  gemm_bat<<<dim3(4, 4, 1), 256, 0, stream>>>(f1, fW2, zp, 512, 0, 0);
  red_ln<<<32, 512, 0, stream>>>(zp, fb2, ln_g, ln_b, lastv, 512, 0);
  gemm_bat<<<dim3(2, 4, 1), 256, 0, stream>>>(lastv, pW1, zp, 256, 0, 0);
  red_ln<<<32, 256, 0, stream>>>(zp, pb1, pln_g, pln_b, pp, 256, 1);
  final9<<<96, 256, 0, stream>>>(pp, pW2, pb2, on_g, on_b, out);
}

// Round 4
// 295.337 us; speedup vs baseline: 2.0186x; 2.0186x over previous
//
#include <hip/hip_runtime.h>
#include <math.h>

// Shapes: B=32, S=512, I=64, H=512, E=8, P=96, O=64, EM=512; D = S*I = 32768.
#define DIMK 32768

__device__ __forceinline__ void fma4(float4& a, float s, const float4 w) {
  a.x += s * w.x; a.y += s * w.y; a.z += s * w.z; a.w += s * w.w;
}

__device__ __forceinline__ float block_sum(float v, float* red, int n) {
  int t = threadIdx.x;
  red[t] = v;
  __syncthreads();
  for (int s = n >> 1; s > 0; s >>= 1) {
    if (t < s) red[t] += red[t + s];
    __syncthreads();
  }
  float r = red[0];
  __syncthreads();
  return r;
}

// ---------------------------------------------------------------------------
// gemm1: part[ks][b][m] = x(32 x 32768)[,k-slice ks] @ gW1[k-slice][m-tile].
// grid (4 mt of 128 m, 128 ks of 256 k), block 256. KC=256 in 4 sub-stages of
// 64 k; W sub-tile register-prefetched (8 float4/thread) then stored to LDS,
// so global loads overlap compute. LDS 66 KB -> 2 blocks/CU.
__global__ __launch_bounds__(256) void gemm1(const float* __restrict__ x,
                                             const float* __restrict__ gW1,
                                             float* __restrict__ part) {
  const int mt = blockIdx.x, ks = blockIdx.y;
  const int m0 = mt * 128, k0 = ks * 256;
  const int t = threadIdx.x;
  __shared__ float As[32 * 260];   // 32 b x 256 k, stride 260 -> bank (4b+k)%32
  __shared__ float Ws[64 * 128];   // one 64k x 128m sub-stage

  // stage A: 2048 float4, 8 per thread (independent, coalesced per b-row)
  for (int i = t; i < 2048; i += 256) {
    int b = i >> 6, q = i & 63;
    *(float4*)&As[b * 260 + q * 4] = *(const float4*)(x + (size_t)b * DIMK + k0 + q * 4);
  }
  // prefetch W sub-stage 0 into registers
  const float* Wp = gW1 + (size_t)k0 * 512 + m0;
  float4 wreg[8];
#pragma unroll
  for (int j = 0; j < 8; ++j) {
    int i = t + j * 256, r = i >> 5, q = i & 31;
    wreg[j] = *(const float4*)(Wp + (size_t)r * 512 + q * 4);
  }

  const int mf = t & 31, bg = t >> 5;
  const int b0 = bg * 4;
  float4 acc[4];
#pragma unroll
  for (int j = 0; j < 4; ++j) acc[j] = make_float4(0.f, 0.f, 0.f, 0.f);
  const float* a0 = &As[b0 * 260];

  for (int s = 0; s < 4; ++s) {
    __syncthreads();  // previous-stage readers done (also covers A stores at s=0)
#pragma unroll
    for (int j = 0; j < 8; ++j) {
      int i = t + j * 256, r = i >> 5, q = i & 31;
      *(float4*)&Ws[r * 128 + q * 4] = wreg[j];
    }
    __syncthreads();
    if (s < 3) {
      const float* Wn = Wp + (size_t)(s + 1) * 64 * 512;
#pragma unroll
      for (int j = 0; j < 8; ++j) {
        int i = t + j * 256, r = i >> 5, q = i & 31;
        wreg[j] = *(const float4*)(Wn + (size_t)r * 512 + q * 4);
      }
    }
    const float* ab = a0 + s * 64;
#pragma unroll 8
    for (int k = 0; k < 64; ++k) {
      float4 wv = *(const float4*)&Ws[k * 128 + mf * 4];
      float av0 = ab[k], av1 = ab[260 + k], av2 = ab[520 + k], av3 = ab[780 + k];
      fma4(acc[0], av0, wv);
      fma4(acc[1], av1, wv);
      fma4(acc[2], av2, wv);
      fma4(acc[3], av3, wv);
    }
  }

  float* op = part + ((size_t)ks * 32 + b0) * 512 + m0 + mf * 4;
#pragma unroll
  for (int j = 0; j < 4; ++j) *(float4*)(op + (size_t)j * 512) = acc[j];
}

// ---------------------------------------------------------------------------
// gred_ln: h1 = relu(LN(sum_ks part + gb1)). grid 32, block 512.
__global__ __launch_bounds__(512) void gred_ln(const float* __restrict__ part,
                                               const float* __restrict__ gb1,
                                               const float* __restrict__ g, const float* __restrict__ bt,
                                               float* __restrict__ h1) {
  const int b = blockIdx.x, t = threadIdx.x;
  __shared__ float red[512];
  float a = gb1[t];
  const float* pp0 = part + (size_t)b * 512 + t;
#pragma unroll 8
  for (int ks = 0; ks < 128; ++ks) a += pp0[(size_t)ks * 16384];
  float mean = block_sum(a, red, 512) * (1.f / 512.f);
  float d = a - mean;
  float var = block_sum(d * d, red, 512) * (1.f / 512.f);
  h1[b * 512 + t] = fmaxf(d * rsqrtf(var + 1e-5f) * g[t] + bt[t], 0.f);
}

// ---------------------------------------------------------------------------
// gemm_tile<KC>: C_part = A(32 x K) @ W(K x M), one (64 m x KC k) tile/block.
// grid (M/64, K/KC, E), block 256. Both A and W tiles staged into LDS with
// coalesced float4 loads (all independent -> one latency round-trip).
// Thread: 2 b x 4 m. Output: part[((kq*E+e)*32+b)*M + m].
template <int KC>
__global__ __launch_bounds__(256) void gemm_tile(const float* __restrict__ A,
                                                 const float* __restrict__ W,
                                                 float* __restrict__ outp,
                                                 int M, int aRow,
                                                 size_t aStrideE, size_t wStrideE) {
  const int mt = blockIdx.x, kq = blockIdx.y, e = blockIdx.z, NE = gridDim.z;
  const int m0 = mt * 64, k0 = kq * KC;
  const int t = threadIdx.x;
  __shared__ float Ws[KC * 64];
  __shared__ float As[32 * (KC + 4)];
  const float* Wp = W + (size_t)e * wStrideE + (size_t)k0 * M + m0;
  for (int i = t; i < KC * 16; i += 256) {
    int r = i >> 4, q = i & 15;
    *(float4*)&Ws[r * 64 + q * 4] = *(const float4*)(Wp + (size_t)r * M + q * 4);
  }
  const float* Ap = A + (size_t)e * aStrideE + k0;
  for (int i = t; i < 32 * (KC / 4); i += 256) {
    int b = i / (KC / 4), q = i % (KC / 4);
    *(float4*)&As[b * (KC + 4) + q * 4] = *(const float4*)(Ap + (size_t)b * aRow + q * 4);
  }
  __syncthreads();
  const int mf = t & 15, bg = t >> 4;
  const int b0 = bg * 2;
  float4 acc0 = make_float4(0.f, 0.f, 0.f, 0.f), acc1 = acc0;
  const float* a0 = &As[b0 * (KC + 4)];
  const float* a1 = &As[(b0 + 1) * (KC + 4)];
#pragma unroll 8
  for (int k = 0; k < KC; ++k) {
    float4 wv = *(const float4*)&Ws[k * 64 + mf * 4];
    fma4(acc0, a0[k], wv);
    fma4(acc1, a1[k], wv);
  }
  float* op = outp + ((size_t)(kq * NE + e) * 32 + b0) * M + m0 + mf * 4;
  *(float4*)op = acc0;
  *(float4*)(op + M) = acc1;
}

// ---------------------------------------------------------------------------
// red_ln: out = [relu](LN(sum_kq zp + bias)). grid 32, block M.
__global__ void red_ln(const float* __restrict__ zp, const float* __restrict__ bias,
                       const float* __restrict__ g, const float* __restrict__ bt,
                       float* __restrict__ outp, int M, int nq, int relu) {
  const int b = blockIdx.x, t = threadIdx.x;
  __shared__ float red[512];
  float a = bias[t];
#pragma unroll 4
  for (int kq = 0; kq < nq; ++kq) a += zp[((size_t)kq * 32 + b) * M + t];
  float fM = 1.f / (float)M;
  float mean = block_sum(a, red, M) * fM;
  float d = a - mean;
  float var = block_sum(d * d, red, M) * fM;
  float v = d * rsqrtf(var + 1e-5f) * g[t] + bt[t];
  outp[b * M + t] = relu ? fmaxf(v, 0.f) : v;
}

// ---------------------------------------------------------------------------
// gate_k: emb = sum_kq zp2 + gb3; d2 to protos; softmax -> wgt. grid 32, block 128.
__global__ __launch_bounds__(128) void gate_k(const float* __restrict__ zp2,
                                              const float* __restrict__ gb3,
                                              const float* __restrict__ protos,
                                              const float* __restrict__ temp,
                                              float* __restrict__ wgt) {
  __shared__ float red[128];
  __shared__ float d2s[8];
  const int b = blockIdx.x, t = threadIdx.x;
  float a = gb3[t];
#pragma unroll 4
  for (int kq = 0; kq < 16; ++kq) a += zp2[((size_t)kq * 32 + b) * 128 + t];
  for (int e = 0; e < 8; ++e) {
    float dd = a - protos[e * 128 + t];
    float s = block_sum(dd * dd, red, 128);
    if (t == 0) d2s[e] = s;
  }
  __syncthreads();
  if (t == 0) {
    float tt = fminf(fmaxf(temp[0], 0.1f), 5.0f);
    float lg[8], mx = -1e30f;
#pragma unroll
    for (int e = 0; e < 8; ++e) {
      float dist = sqrtf(fmaxf(d2s[e], 1e-12f));
      lg[e] = -dist / tt;
      mx = fmaxf(mx, lg[e]);
    }
    float se = 0.f;
#pragma unroll
    for (int e = 0; e < 8; ++e) { lg[e] = expf(lg[e] - mx); se += lg[e]; }
#pragma unroll
    for (int e = 0; e < 8; ++e) wgt[b * 8 + e] = lg[e] / se;
  }
}

// ---------------------------------------------------------------------------
// he_k: he_all[e][b][h] = relu(x_last[b] . eW1[e][:,h] + eb1[e][h]).
// grid (8 e, 2 h-halves), block 256. eW1 half-tile (64x256 = 64 KB) staged in LDS.
__global__ __launch_bounds__(256) void he_k(const float* __restrict__ x,
                                            const float* __restrict__ eW1,
                                            const float* __restrict__ eb1,
                                            float* __restrict__ he_all) {
  const int e = blockIdx.x, hs = blockIdx.y;
  const int t = threadIdx.x;
  __shared__ float xs[32 * 64];
  __shared__ float Ws[64 * 256];
  for (int i = t; i < 512; i += 256) {  // xs: 512 float4
    int b = i >> 4, q = i & 15;
    *(float4*)&xs[b * 64 + q * 4] = *(const float4*)(x + (size_t)b * DIMK + 32704 + q * 4);
  }
  const float* w1 = eW1 + (size_t)e * 64 * 512 + hs * 256;
  for (int i = t; i < 64 * 64; i += 256) {  // Ws: 4096 float4, 16/thread
    int k = i >> 6, q = i & 63;
    *(float4*)&Ws[k * 256 + q * 4] = *(const float4*)(w1 + (size_t)k * 512 + q * 4);
  }
  __syncthreads();
  float acc[32];
#pragma unroll
  for (int b = 0; b < 32; ++b) acc[b] = 0.f;
#pragma unroll 4
  for (int k = 0; k < 64; ++k) {
    float wk = Ws[k * 256 + t];
#pragma unroll
    for (int b = 0; b < 32; ++b) acc[b] += xs[b * 64 + k] * wk;
  }
  float bb = eb1[e * 512 + hs * 256 + t];
  for (int b = 0; b < 32; ++b)
    he_all[((size_t)e * 32 + b) * 512 + hs * 256 + t] = fmaxf(acc[b] + bb, 0.f);
}

// ---------------------------------------------------------------------------
// ffuse: fused[b] = sum_e w[b,e]*(sum_kq epart[kq][e][b] + eb2[e]). grid 32, block 512.
__global__ __launch_bounds__(512) void ffuse(const float* __restrict__ epart,
                                             const float* __restrict__ eb2,
                                             const float* __restrict__ wgt,
                                             float* __restrict__ fused) {
  const int b = blockIdx.x, t = threadIdx.x;
  __shared__ float wl[8];
  if (t < 8) wl[t] = wgt[b * 8 + t];
  __syncthreads();
  float a = 0.f;
#pragma unroll
  for (int e = 0; e < 8; ++e) {
    float s = eb2[e * 512 + t];
#pragma unroll
    for (int kq = 0; kq < 8; ++kq)
      s += epart[(((size_t)kq * 8 + e) * 32 + b) * 512 + t];
    a += wl[e] * s;
  }
  fused[b * 512 + t] = a;
}

// ---------------------------------------------------------------------------
// fin_red: out[b][pi][o] = LN_o(sum_kq fpart + pb2). block 256 = 4 rows of 64
// lanes; grid 768 (3072 rows / 4).
__global__ __launch_bounds__(256) void fin_red(const float* __restrict__ fpart,
                                               const float* __restrict__ pb2,
                                               const float* __restrict__ ong,
                                               const float* __restrict__ onb,
                                               float* __restrict__ outp) {
  const int t = threadIdx.x;
  const int lane = t & 63, w = t >> 6;
  const int r = blockIdx.x * 4 + w;  // 0..3071
  const int b = r / 96, pi = r % 96;
  const int m = pi * 64 + lane;
  float a = pb2[m];
#pragma unroll
  for (int kq = 0; kq < 8; ++kq) a += fpart[((size_t)kq * 32 + b) * 6144 + m];
  float s = a;
  s += __shfl_xor(s, 1); s += __shfl_xor(s, 2); s += __shfl_xor(s, 4);
  s += __shfl_xor(s, 8); s += __shfl_xor(s, 16); s += __shfl_xor(s, 32);
  float mean = s * (1.f / 64.f);
  float d = a - mean;
  float q = d * d;
  q += __shfl_xor(q, 1); q += __shfl_xor(q, 2); q += __shfl_xor(q, 4);
  q += __shfl_xor(q, 8); q += __shfl_xor(q, 16); q += __shfl_xor(q, 32);
  float rr = rsqrtf(q * (1.f / 64.f) + 1e-5f);
  outp[((size_t)b * 96 + pi) * 64 + lane] = d * rr * ong[lane] + onb[lane];
}

extern "C" void kernel_launch(void* const* d_in, const int* in_sizes, int n_in,
                              void* d_out, int out_size, void* d_ws, size_t ws_size,
                              hipStream_t stream) {
  (void)in_sizes; (void)n_in; (void)out_size; (void)ws_size;
  const float* x      = (const float*)d_in[0];
  const float* gW1    = (const float*)d_in[1];
  const float* gb1    = (const float*)d_in[2];
  const float* gln1_g = (const float*)d_in[3];
  const float* gln1_b = (const float*)d_in[4];
  const float* gW2    = (const float*)d_in[5];
  const float* gb2    = (const float*)d_in[6];
  const float* gln2_g = (const float*)d_in[7];
  const float* gln2_b = (const float*)d_in[8];
  const float* gW3    = (const float*)d_in[9];
  const float* gb3    = (const float*)d_in[10];
  const float* protos = (const float*)d_in[11];
  const float* temp   = (const float*)d_in[12];
  const float* eW1    = (const float*)d_in[13];
  const float* eb1    = (const float*)d_in[14];
  const float* eW2    = (const float*)d_in[15];
  const float* eb2    = (const float*)d_in[16];
  const float* fW1    = (const float*)d_in[17];
  const float* fb1    = (const float*)d_in[18];
  const float* fln_g  = (const float*)d_in[19];
  const float* fln_b  = (const float*)d_in[20];
  const float* fW2    = (const float*)d_in[21];
  const float* fb2    = (const float*)d_in[22];
  const float* ln_g   = (const float*)d_in[23];
  const float* ln_b   = (const float*)d_in[24];
  const float* pW1    = (const float*)d_in[25];
  const float* pb1    = (const float*)d_in[26];
  const float* pln_g  = (const float*)d_in[27];
  const float* pln_b  = (const float*)d_in[28];
  const float* pW2    = (const float*)d_in[29];
  const float* pb2    = (const float*)d_in[30];
  const float* on_g   = (const float*)d_in[31];
  const float* on_b   = (const float*)d_in[32];
  float* out = (float*)d_out;

  float* ws     = (float*)d_ws;
  // region 0 (2,097,152 floats): gemm1 partials; after gred_ln reused as
  //   epart [0 .. 1,048,576) and he_all [1,048,576 .. 1,179,648);
  //   after ffuse reused as fpart [0 .. 1,572,864).
  float* part   = ws;
  float* epart  = ws;
  float* he_all = ws + 1048576;
  float* fpart  = ws;
  float* h1     = ws + 2097152;     // 16384
  float* h2     = h1 + 16384;
  float* zp     = h2 + 16384;       // 262144 (16 kq x 32 x 512)
  float* zp2    = zp + 262144;      // 65536 (16 kq x 32 x 128)
  float* wgt    = zp2 + 65536;      // 256
  float* fused  = wgt + 256;        // 16384
  float* f1     = fused + 16384;    // 16384
  float* lastv  = f1 + 16384;       // 16384
  float* pp     = lastv + 16384;    // 8192

  // g-path
  gemm1<<<dim3(4, 128), 256, 0, stream>>>(x, gW1, part);
  gred_ln<<<32, 512, 0, stream>>>(part, gb1, gln1_g, gln1_b, h1);
  gemm_tile<32><<<dim3(8, 16, 1), 256, 0, stream>>>(h1, gW2, zp, 512, 512, 0, 0);
  red_ln<<<32, 512, 0, stream>>>(zp, gb2, gln2_g, gln2_b, h2, 512, 16, 1);
  gemm_tile<32><<<dim3(2, 16, 1), 256, 0, stream>>>(h2, gW3, zp2, 128, 512, 0, 0);
  gate_k<<<32, 128, 0, stream>>>(zp2, gb3, protos, temp, wgt);

  // expert path (reuses region 0 after gred_ln)
  he_k<<<dim3(8, 2), 256, 0, stream>>>(x, eW1, eb1, he_all);
  gemm_tile<64><<<dim3(8, 8, 8), 256, 0, stream>>>(he_all, eW2, epart, 512, 512,
                                                   (size_t)32 * 512, (size_t)512 * 512);
  ffuse<<<32, 512, 0, stream>>>(epart, eb2, wgt, fused);

  // f-path
  gemm_tile<32><<<dim3(8, 16, 1), 256, 0, stream>>>(fused, fW1, zp, 512, 512, 0, 0);
  red_ln<<<32, 512, 0, stream>>>(zp, fb1, fln_g, fln_b, f1, 512, 16, 1);
  gemm_tile<32><<<dim3(8, 16, 1), 256, 0, stream>>>(f1, fW2, zp, 512, 512, 0, 0);
  red_ln<<<32, 512, 0, stream>>>(zp, fb2, ln_g, ln_b, lastv, 512, 16, 0);
  gemm_tile<32><<<dim3(4, 16, 1), 256, 0, stream>>>(lastv, pW1, zp, 256, 512, 0, 0);
  red_ln<<<32, 256, 0, stream>>>(zp, pb1, pln_g, pln_b, pp, 256, 16, 1);

  // final projection + LN(64)
  gemm_tile<32><<<dim3(96, 8, 1), 256, 0, stream>>>(pp, pW2, fpart, 6144, 256, 0, 0);
  fin_red<<<768, 256, 0, stream>>>(fpart, pb2, on_g, on_b, out);
}